// Round 9
// baseline (428.353 us; speedup 1.0000x reference)
//
#include <hip/hip_runtime.h>
#include <hip/hip_fp16.h>
#include <math.h>

#define ITERS 12

typedef __attribute__((ext_vector_type(8))) short short8;
typedef __attribute__((ext_vector_type(4))) float float4v;

static __device__ inline unsigned short f2bf(float f) {
    union { float f; unsigned int u; } c; c.f = f;
    unsigned int u = c.u;
    u += 0x7fffu + ((u >> 16) & 1u);          // round-to-nearest-even
    return (unsigned short)(u >> 16);
}
static __device__ inline float bf2f(unsigned short h) {
    union { float f; unsigned int u; } c; c.u = ((unsigned int)h) << 16;
    return c.f;
}

// ---------------------------------------------------------------------------
// Kernel A: P = l2_normalize(X @ W^T + b), emitted as split-bf16 rows of 192:
//   sub:  [hi(64) | lo(64) | hi(64)]
//   edge: [hi(64) | hi(64) | lo(64)]
// subE @ edgeE^T over K=192 = Ah*Bh + Al*Bh + Ah*Bl (lo*lo dropped).
// Unchanged from r5/r7 (known-pass).
// ---------------------------------------------------------------------------
__global__ __launch_bounds__(256) void proj_norm_kernel(
    const float* __restrict__ Xsub, const float* __restrict__ Xedge,
    const float* __restrict__ Wsub, const float* __restrict__ bsub,
    const float* __restrict__ Wedge, const float* __restrict__ bedge,
    unsigned short* __restrict__ subE, unsigned short* __restrict__ edgeE)
{
    const int mat = blockIdx.y;
    const float* X  = mat ? Xedge : Xsub;
    const float* W  = mat ? Wedge : Wsub;
    const float* Bv = mat ? bedge : bsub;
    unsigned short* OUT = mat ? edgeE : subE;

    const int r0 = blockIdx.x * 32;
    const int t  = threadIdx.x;
    const int tx = t & 15, ty = t >> 4;

    __shared__ float xs[64 * 34];   // [k][row(32)+pad]
    __shared__ float ws[64 * 68];   // [k][col(64)+pad]

    float acc[2][4] = {};

    for (int ch = 0; ch < 8; ++ch) {
        const int kb = ch * 64;
#pragma unroll
        for (int i = 0; i < 2; ++i) {
            int e = t + 256 * i;            // 512 float4 (32 rows x 16 kq)
            int row = e & 31, kq = e >> 5;
            float4 xv = *(const float4*)(X + (size_t)(r0 + row) * 512 + kb + kq * 4);
            xs[(kq * 4 + 0) * 34 + row] = xv.x;
            xs[(kq * 4 + 1) * 34 + row] = xv.y;
            xs[(kq * 4 + 2) * 34 + row] = xv.z;
            xs[(kq * 4 + 3) * 34 + row] = xv.w;
        }
#pragma unroll
        for (int i = 0; i < 4; ++i) {
            int e = t + 256 * i;            // 1024 float4 (64 cols x 16 kq)
            int col = e & 63, kq = e >> 6;
            float4 wv = *(const float4*)(W + (size_t)col * 512 + kb + kq * 4);
            ws[(kq * 4 + 0) * 68 + col] = wv.x;
            ws[(kq * 4 + 1) * 68 + col] = wv.y;
            ws[(kq * 4 + 2) * 68 + col] = wv.z;
            ws[(kq * 4 + 3) * 68 + col] = wv.w;
        }
        __syncthreads();
#pragma unroll 8
        for (int k = 0; k < 64; ++k) {
            const float2 a2 = *(const float2*)&xs[k * 34 + ty * 2];
            const float4 b4 = *(const float4*)&ws[k * 68 + tx * 4];
            acc[0][0] = fmaf(a2.x, b4.x, acc[0][0]);
            acc[0][1] = fmaf(a2.x, b4.y, acc[0][1]);
            acc[0][2] = fmaf(a2.x, b4.z, acc[0][2]);
            acc[0][3] = fmaf(a2.x, b4.w, acc[0][3]);
            acc[1][0] = fmaf(a2.y, b4.x, acc[1][0]);
            acc[1][1] = fmaf(a2.y, b4.y, acc[1][1]);
            acc[1][2] = fmaf(a2.y, b4.z, acc[1][2]);
            acc[1][3] = fmaf(a2.y, b4.w, acc[1][3]);
        }
        __syncthreads();
    }

    const float4 bb = *(const float4*)(Bv + tx * 4);
#pragma unroll
    for (int i = 0; i < 2; ++i) {
        acc[i][0] += bb.x; acc[i][1] += bb.y; acc[i][2] += bb.z; acc[i][3] += bb.w;
        float s = acc[i][0]*acc[i][0] + acc[i][1]*acc[i][1]
                + acc[i][2]*acc[i][2] + acc[i][3]*acc[i][3];
#pragma unroll
        for (int off = 1; off <= 8; off <<= 1)
            s += __shfl_xor(s, off, 64);
        const float inv = 1.0f / fmaxf(sqrtf(s), 1e-12f);

        unsigned short h[4], l[4];
#pragma unroll
        for (int j = 0; j < 4; ++j) {
            const float v = acc[i][j] * inv;
            h[j] = f2bf(v);
            l[j] = f2bf(v - bf2f(h[j]));
        }
        uint2 hp, lp;
        hp.x = (unsigned)h[0] | ((unsigned)h[1] << 16);
        hp.y = (unsigned)h[2] | ((unsigned)h[3] << 16);
        lp.x = (unsigned)l[0] | ((unsigned)l[1] << 16);
        lp.y = (unsigned)l[2] | ((unsigned)l[3] << 16);

        unsigned short* base = OUT + (size_t)(r0 + ty * 2 + i) * 192 + tx * 4;
        *(uint2*)(base)       = hp;
        *(uint2*)(base + 64)  = mat ? hp : lp;   // edge: hi ; sub: lo
        *(uint2*)(base + 128) = mat ? lp : hp;   // edge: lo ; sub: hi
    }
}

// ---------------------------------------------------------------------------
// Kernel B1 (MFMA v3): z[s][e] = fp16( dot * scale / 2 ), bf16 GEMM K=192.
// EXACT r7 skeleton (tile 128(M) x 64(N), acc 4x2, bounds (256,4), 27.6 KB
// LDS, 8192 blocks) with ONLY the r8-validated operand swap applied:
// M = e (A = edgeE), N = s (B = subE) -> a lane's 4 C-regs are 4 CONSECUTIVE
// e at fixed s -> one packed 8-B float2 store per 16x16 tile (r7 did 4
// scalar 2-B stores to 4 different rows).
// Wave quadrant: mrow0=(wid&1)*64 over e (4 m-tiles), ncol0=(wid>>1)*32
// over s (2 n-tiles). K staged in 3 chunks of 64, LDS stride 72 shorts.
// C/D layout (r8 first-call validated): col(N=s)=lane&15, row(M=e)=quad*4+reg.
// ---------------------------------------------------------------------------
__global__ __launch_bounds__(256, 4) void score_mfma_kernel(
    const unsigned short* __restrict__ subE,
    const unsigned short* __restrict__ edgeE,
    const float* __restrict__ log_scale, __half* __restrict__ z)
{
    const int t    = threadIdx.x;
    const int lane = t & 63;
    const int wid  = t >> 6;
    const int li   = lane & 15;
    const int quad = lane >> 4;
    const int e0   = blockIdx.x * 128;   // M
    const int s0   = blockIdx.y * 64;    // N
    const int mrow0 = (wid & 1) * 64;
    const int ncol0 = (wid >> 1) * 32;

    __shared__ unsigned short eS[128 * 72];   // A (edge) chunk, k-contig
    __shared__ unsigned short sS[64 * 72];    // B (sub)  chunk, k-contig

    float4v acc[4][2];
#pragma unroll
    for (int mi = 0; mi < 4; ++mi)
#pragma unroll
        for (int ni = 0; ni < 2; ++ni)
            acc[mi][ni] = (float4v){0.f, 0.f, 0.f, 0.f};

    for (int c = 0; c < 3; ++c) {
        if (c) __syncthreads();             // protect LDS reuse
#pragma unroll
        for (int i = 0; i < 4; ++i) {
            int e = t + 256 * i;            // 1024 f4 (128 rows x 8 offs)
            int row = e >> 3, off = e & 7;
            *(float4*)&eS[row * 72 + off * 8] =
                *(const float4*)(edgeE + (size_t)(e0 + row) * 192 + c * 64 + off * 8);
        }
#pragma unroll
        for (int i = 0; i < 2; ++i) {
            int e = t + 256 * i;            // 512 f4 (64 rows x 8 offs)
            int row = e >> 3, off = e & 7;
            *(float4*)&sS[row * 72 + off * 8] =
                *(const float4*)(subE + (size_t)(s0 + row) * 192 + c * 64 + off * 8);
        }
        __syncthreads();

#pragma unroll
        for (int ks = 0; ks < 2; ++ks) {
            short8 af[4], bf[2];
#pragma unroll
            for (int mi = 0; mi < 4; ++mi)
                af[mi] = *(const short8*)&eS[(mrow0 + mi * 16 + li) * 72 + ks * 32 + quad * 8];
#pragma unroll
            for (int ni = 0; ni < 2; ++ni)
                bf[ni] = *(const short8*)&sS[(ncol0 + ni * 16 + li) * 72 + ks * 32 + quad * 8];
#pragma unroll
            for (int mi = 0; mi < 4; ++mi)
#pragma unroll
                for (int ni = 0; ni < 2; ++ni)
                    acc[mi][ni] = __builtin_amdgcn_mfma_f32_16x16x32_bf16(
                        af[mi], bf[ni], acc[mi][ni], 0, 0, 0);
        }
    }

    float sc = expf(log_scale[0]);
    sc = fminf(fmaxf(sc, 0.5f), 20.0f);
    const float zs = sc * 0.5f;             // z = scores/2

    // C/D: col(N=s)=li, row(M=e)=quad*4+reg -> 4 consecutive e per lane.
#pragma unroll
    for (int ni = 0; ni < 2; ++ni) {
        const size_t srow = (size_t)(s0 + ncol0 + ni * 16 + li) * 8192;
#pragma unroll
        for (int mi = 0; mi < 4; ++mi) {
            const int eb = e0 + mrow0 + mi * 16 + quad * 4;
            __half2 h0, h1;
            h0.x = __float2half_rn(acc[mi][ni][0] * zs);
            h0.y = __float2half_rn(acc[mi][ni][1] * zs);
            h1.x = __float2half_rn(acc[mi][ni][2] * zs);
            h1.y = __float2half_rn(acc[mi][ni][3] * zs);
            __half2 pair[2] = {h0, h1};
            *(float2*)(z + srow + eb) = *(const float2*)pair;
        }
    }
}

// ---------------------------------------------------------------------------
// Kernel B2: rowwise exact 1.5-entmax on fp16 z (unchanged r5/r7).
// ---------------------------------------------------------------------------
__global__ __launch_bounds__(256) void entmax_fp16_kernel(
    const __half* __restrict__ z, float* __restrict__ out)
{
    const int row  = blockIdx.x;
    const int t    = threadIdx.x;
    const int lane = t & 63, wid = t >> 6;
    const __half* zr = z + (size_t)row * 8192;

    float4 rd[4];
#pragma unroll
    for (int c = 0; c < 4; ++c)
        rd[c] = *(const float4*)(zr + c * 2048 + t * 8);

    float zv[32];
#pragma unroll
    for (int c = 0; c < 4; ++c) {
        const __half2* p = (const __half2*)&rd[c];
#pragma unroll
        for (int j = 0; j < 4; ++j) {
            float2 f2 = __half22float2(p[j]);
            zv[c * 8 + j * 2 + 0] = f2.x;
            zv[c * 8 + j * 2 + 1] = f2.y;
        }
    }

    __shared__ float tblm[4];
    __shared__ float tbl[2][4][3];

    float m = -1e30f;
#pragma unroll
    for (int i = 0; i < 32; ++i) m = fmaxf(m, zv[i]);
#pragma unroll
    for (int off = 32; off; off >>= 1) m = fmaxf(m, __shfl_xor(m, off, 64));
    if (lane == 0) tblm[wid] = m;
    __syncthreads();
    m = fmaxf(fmaxf(tblm[0], tblm[1]), fmaxf(tblm[2], tblm[3]));

    float tau = m - 1.0f;

    for (int it = 0; it < ITERS; ++it) {
        float n = 0.f, s1 = 0.f, s2 = 0.f;
#pragma unroll
        for (int i = 0; i < 32; ++i) {
            const float e_  = zv[i];
            const bool  p_  = e_ > tau;
            const float zm_ = p_ ? e_ : 0.0f;
            n  += p_ ? 1.0f : 0.0f;
            s1 += zm_;
            s2  = fmaf(zm_, e_, s2);
        }
#pragma unroll
        for (int off = 32; off; off >>= 1) {
            n  += __shfl_xor(n,  off, 64);
            s1 += __shfl_xor(s1, off, 64);
            s2 += __shfl_xor(s2, off, 64);
        }
        if (lane == 0) {
            tbl[it & 1][wid][0] = n;
            tbl[it & 1][wid][1] = s1;
            tbl[it & 1][wid][2] = s2;
        }
        __syncthreads();
        float N = 0.f, S1 = 0.f, S2 = 0.f;
#pragma unroll
        for (int w = 0; w < 4; ++w) {
            N  += tbl[it & 1][w][0];
            S1 += tbl[it & 1][w][1];
            S2 += tbl[it & 1][w][2];
        }
        const float disc = S1 * S1 - N * (S2 - 1.0f);
        float tn;
        if (disc >= 0.0f) {
            tn = (S1 - sqrtf(disc)) / N;
        } else {
            const float g = S1 - N * tau;
            const float f = S2 - tau * (2.0f * S1 - N * tau);
            tn = tau + (f - 1.0f) / (2.0f * g);
        }
        if (tn == tau) break;
        tau = tn;
    }

#pragma unroll
    for (int c = 0; c < 4; ++c) {
        float4 p0, p1; float d;
        d = fmaxf(zv[c*8+0] - tau, 0.f); p0.x = d * d;
        d = fmaxf(zv[c*8+1] - tau, 0.f); p0.y = d * d;
        d = fmaxf(zv[c*8+2] - tau, 0.f); p0.z = d * d;
        d = fmaxf(zv[c*8+3] - tau, 0.f); p0.w = d * d;
        d = fmaxf(zv[c*8+4] - tau, 0.f); p1.x = d * d;
        d = fmaxf(zv[c*8+5] - tau, 0.f); p1.y = d * d;
        d = fmaxf(zv[c*8+6] - tau, 0.f); p1.z = d * d;
        d = fmaxf(zv[c*8+7] - tau, 0.f); p1.w = d * d;
        float* op = out + (size_t)row * 8192 + c * 2048 + t * 8;
        *(float4*)op       = p0;
        *(float4*)(op + 4) = p1;
    }
}

// ---------------------------------------------------------------------------
extern "C" void kernel_launch(void* const* d_in, const int* in_sizes, int n_in,
                              void* d_out, int out_size, void* d_ws, size_t ws_size,
                              hipStream_t stream)
{
    const float* edge_repr = (const float*)d_in[0];
    const float* sub_repr  = (const float*)d_in[1];
    const float* W_sub     = (const float*)d_in[2];
    const float* b_sub     = (const float*)d_in[3];
    const float* W_edge    = (const float*)d_in[4];
    const float* b_edge    = (const float*)d_in[5];
    const float* log_scale = (const float*)d_in[6];
    float* out = (float*)d_out;

    unsigned short* subE  = (unsigned short*)d_ws;                 // 3 MB
    unsigned short* edgeE = subE + (size_t)8192 * 192;             // 3 MB
    __half*         zbuf  = (__half*)(edgeE + (size_t)8192 * 192); // 134 MB

    proj_norm_kernel<<<dim3(256, 2), 256, 0, stream>>>(
        sub_repr, edge_repr, W_sub, b_sub, W_edge, b_edge, subE, edgeE);

    score_mfma_kernel<<<dim3(64, 128), 256, 0, stream>>>(
        subE, edgeE, log_scale, zbuf);

    entmax_fp16_kernel<<<8192, 256, 0, stream>>>(zbuf, out);
}